// Round 12
// baseline (47.976 us; speedup 1.0000x reference)
//
#include <hip/hip_runtime.h>
#include <math.h>

#define BATCH 16
#define TQL   2048
#define TKL   1024
#define DDEC  256
#define DENC  256
#define DATT  128
#define WIN   3

// workspace layout (floats):
//   kq : 48*256   @ 0        (Wq^T-folded keys:  s_j = q . kq + kb)
//   vo : 48*256   @ 12288    (Wo-folded values:  ctx@Wo^T = 32 * sum a_j vo_j)
//   kb : 48       @ 24576
#define WS_KQ 0
#define WS_VO (48*DDEC)
#define WS_KB (2*48*DDEC)

// ---------------------------------------------------------------------------
// L0: folded-weight precompute, role-split (96 blocks) — verified in R10/R11.
// ---------------------------------------------------------------------------
__global__ __launch_bounds__(256) void precompute(
    const float* __restrict__ keys, const float* __restrict__ values,
    const float* __restrict__ Wk, const float* __restrict__ bk,
    const float* __restrict__ Wv, const float* __restrict__ bv,
    const float* __restrict__ Wq, const float* __restrict__ bq,
    const float* __restrict__ Wo, const int* __restrict__ pidx,
    float* __restrict__ ws)
{
    const int blk  = blockIdx.x;       // 0..95
    const int pair = blk >> 1;         // 0..47
    const int role = blk & 1;
    const int b = pair / WIN, j = pair % WIN;
    const int prev = pidx[0];
    const int col = prev + j;
    const bool valid = (col >= 0) && (col < TKL);
    const int t = threadIdx.x;

    __shared__ float src[DENC];
    __shared__ float mid[DATT];

    {
        const float* base = role ? values : keys;
        size_t idx = ((size_t)b * TKL + (valid ? col : 0)) * DENC + t;
        src[t] = valid ? base[idx] : 0.0f;
    }
    __syncthreads();

    if (t < DATT) {
        const float4* wrow = (const float4*)((role ? Wv : Wk) + (size_t)t * DENC);
        float acc = 0.0f;
        #pragma unroll 8
        for (int k4 = 0; k4 < DENC / 4; ++k4) {
            float4 w = wrow[k4];
            acc += w.x * src[k4*4+0] + w.y * src[k4*4+1]
                 + w.z * src[k4*4+2] + w.w * src[k4*4+3];
        }
        mid[t] = acc + (role ? bv[t] : bk[t]);
    }
    __syncthreads();

    if (role == 0) {
        float accq = 0.0f;
        #pragma unroll 4
        for (int c = 0; c < DATT; ++c)
            accq += mid[c] * Wq[(size_t)c * DDEC + t];
        ws[WS_KQ + pair * DDEC + t] = accq;
        if (t < 64) {
            float pb = bq[t] * mid[t] + bq[t + 64] * mid[t + 64];
            #pragma unroll
            for (int off = 32; off > 0; off >>= 1) pb += __shfl_xor(pb, off, 64);
            if (t == 0) ws[WS_KB + pair] = pb;
        }
    } else {
        const float4* worow = (const float4*)(Wo + (size_t)t * DATT);
        float acco = 0.0f;
        #pragma unroll 4
        for (int c4 = 0; c4 < DATT / 4; ++c4) {
            float4 w = worow[c4];
            acco += w.x * mid[c4*4+0] + w.y * mid[c4*4+1]
                  + w.z * mid[c4*4+2] + w.w * mid[c4*4+3];
        }
        ws[WS_VO + pair * DDEC + t] = acco;
    }
}

// ---------------------------------------------------------------------------
// Fused main: 2048 blocks x 16 rows; each WAVE owns 4 rows end-to-end.
// Schedule per wave: q loads -> operand loads (L2) -> full-width attn zero
// stores for its 4 rows (soak the memory pipe under q latency) -> per-row
// softmax -> out row store -> overwrite window float4s in its OWN rows
// (same lane that wrote the zero => program-order; line is L2-hot).
// No barriers, no LDS staging, no holed stores, no cross-wave races.
// ---------------------------------------------------------------------------
__device__ __forceinline__ float winval(int ww, float w0, float w1, float w2) {
    float v = (ww == 0) ? w0 : ((ww == 1) ? w1 : ((ww == 2) ? w2 : 0.0f));
    return (ww >= 0 && ww < WIN) ? v : 0.0f;
}

__global__ __launch_bounds__(256) void attn_fused(
    const float* __restrict__ query, const float* __restrict__ bo,
    const int* __restrict__ pidx, const float* __restrict__ ws,
    float* __restrict__ out, float* __restrict__ attn)
{
    const int t    = threadIdx.x;
    const int lane = t & 63;
    const int wid  = t >> 6;                 // wave 0..3
    const int blk  = blockIdx.x;             // 0..2047, 16 rows each
    const int b    = blk >> 7;               // 128 blocks per batch
    const int base = b * WIN;
    const int prev = pidx[0];
    const int row0 = blk * 16 + wid * 4;

    // ---- q loads first (longest latency) ----
    const float4* qp = (const float4*)query;
    float4 q[4];
    #pragma unroll
    for (int r = 0; r < 4; ++r)
        q[r] = qp[(size_t)(row0 + r) * 64 + lane];

    // ---- operands: 1 f4/lane each (L2-hot, 48KB unique per batch) ----
    const float4* kq4 = (const float4*)(ws + WS_KQ) + (size_t)base * 64;
    const float4* vo4 = (const float4*)(ws + WS_VO) + (size_t)base * 64;
    const float4 K0 = kq4[      lane];
    const float4 K1 = kq4[ 64 + lane];
    const float4 K2 = kq4[128 + lane];
    const float4 V0 = vo4[      lane];
    const float4 V1 = vo4[ 64 + lane];
    const float4 V2 = vo4[128 + lane];
    const float4 B4 = ((const float4*)bo)[lane];
    const float kb0 = ws[WS_KB + base + 0];
    const float kb1 = ws[WS_KB + base + 1];
    const float kb2 = ws[WS_KB + base + 2];

    // ---- full-width zero stores for this wave's 4 attn rows ----
    const float4 z4 = make_float4(0.0f, 0.0f, 0.0f, 0.0f);
    #pragma unroll
    for (int r = 0; r < 4; ++r) {
        float4* ar = (float4*)(attn + (size_t)(row0 + r) * TKL);
        #pragma unroll
        for (int i = 0; i < 4; ++i) ar[i * 64 + lane] = z4;   // 1KB/instr
    }

    // ---- window f4 indices (uniform) ----
    int lo = prev < 0 ? 0 : prev;
    int hi = prev + (WIN - 1) > TKL - 1 ? TKL - 1 : prev + (WIN - 1);
    int f0 = -1, f1 = -1;
    if (lo <= hi) { f0 = lo >> 2; f1 = hi >> 2; }

    const bool v0 = (prev + 0 >= 0) && (prev + 0 < TKL);
    const bool v1 = (prev + 1 >= 0) && (prev + 1 < TKL);
    const bool v2 = (prev + 2 >= 0) && (prev + 2 < TKL);

    const float CTX_SCALE = 32.0f;            // Tk * sqrt(1/Tk) = sqrt(1024)
    const float RSQ2 = 0.70710678118654752f;  // sqrt(0.5)
    const float NEG = -3.0e38f;

    #pragma unroll
    for (int r = 0; r < 4; ++r) {
        const int row = row0 + r;
        const float4 qq = q[r];

        float p0 = qq.x*K0.x + qq.y*K0.y + qq.z*K0.z + qq.w*K0.w;
        float p1 = qq.x*K1.x + qq.y*K1.y + qq.z*K1.z + qq.w*K1.w;
        float p2 = qq.x*K2.x + qq.y*K2.y + qq.z*K2.z + qq.w*K2.w;

        #pragma unroll
        for (int off = 32; off > 0; off >>= 1) {
            p0 += __shfl_xor(p0, off, 64);
            p1 += __shfl_xor(p1, off, 64);
            p2 += __shfl_xor(p2, off, 64);
        }

        float s0 = v0 ? (p0 + kb0) : NEG;
        float s1 = v1 ? (p1 + kb1) : NEG;
        float s2 = v2 ? (p2 + kb2) : NEG;

        const float m  = fmaxf(s0, fmaxf(s1, s2));
        const float e0 = v0 ? __expf(s0 - m) : 0.0f;
        const float e1 = v1 ? __expf(s1 - m) : 0.0f;
        const float e2 = v2 ? __expf(s2 - m) : 0.0f;
        const float inv = 1.0f / (e0 + e1 + e2);
        const float w0 = e0 * inv, w1 = e1 * inv, w2 = e2 * inv;

        // out row (1KB coalesced)
        float4 o;
        o.x = (CTX_SCALE * (w0*V0.x + w1*V1.x + w2*V2.x) + B4.x + qq.x) * RSQ2;
        o.y = (CTX_SCALE * (w0*V0.y + w1*V1.y + w2*V2.y) + B4.y + qq.y) * RSQ2;
        o.z = (CTX_SCALE * (w0*V0.z + w1*V1.z + w2*V2.z) + B4.z + qq.z) * RSQ2;
        o.w = (CTX_SCALE * (w0*V0.w + w1*V1.w + w2*V2.w) + B4.w + qq.w) * RSQ2;
        ((float4*)(out + (size_t)row * DDEC))[lane] = o;

        // window overwrite in OWN row; same lane that wrote the zero
        float4* ar = (float4*)(attn + (size_t)row * TKL);
        if (f0 >= 0 && (f0 & 63) == lane) {
            const int c0 = f0 * 4;
            float4 pz;
            pz.x = winval(c0 + 0 - prev, w0, w1, w2);
            pz.y = winval(c0 + 1 - prev, w0, w1, w2);
            pz.z = winval(c0 + 2 - prev, w0, w1, w2);
            pz.w = winval(c0 + 3 - prev, w0, w1, w2);
            ar[f0] = pz;
        }
        if (f1 != f0 && (f1 & 63) == lane) {
            const int c0 = f1 * 4;
            float4 pz;
            pz.x = winval(c0 + 0 - prev, w0, w1, w2);
            pz.y = winval(c0 + 1 - prev, w0, w1, w2);
            pz.z = winval(c0 + 2 - prev, w0, w1, w2);
            pz.w = winval(c0 + 3 - prev, w0, w1, w2);
            ar[f1] = pz;
        }
    }
}

extern "C" void kernel_launch(void* const* d_in, const int* in_sizes, int n_in,
                              void* d_out, int out_size, void* d_ws, size_t ws_size,
                              hipStream_t stream)
{
    const float* query  = (const float*)d_in[0];
    const float* keys   = (const float*)d_in[1];
    const float* values = (const float*)d_in[2];
    const float* Wq     = (const float*)d_in[3];
    const float* bq     = (const float*)d_in[4];
    const float* Wk     = (const float*)d_in[5];
    const float* bk     = (const float*)d_in[6];
    const float* Wv     = (const float*)d_in[7];
    const float* bv     = (const float*)d_in[8];
    const float* Wo     = (const float*)d_in[9];
    const float* bo     = (const float*)d_in[10];
    const int*   pidx   = (const int*)d_in[11];

    float* ws   = (float*)d_ws;
    float* out  = (float*)d_out;
    float* attn = out + (size_t)BATCH * TQL * DDEC;

    precompute<<<96, 256, 0, stream>>>(keys, values, Wk, bk, Wv, bv,
                                       Wq, bq, Wo, pidx, ws);
    attn_fused<<<2048, 256, 0, stream>>>(query, bo, pidx, ws, out, attn);
}

// Round 13
// 40.217 us; speedup vs baseline: 1.1929x; 1.1929x over previous
//
#include <hip/hip_runtime.h>
#include <math.h>

#define BATCH 16
#define TQL   2048
#define TKL   1024
#define DDEC  256
#define DENC  256
#define DATT  128
#define WIN   3

// workspace layout (floats):
//   kq : 48*256  @ 0       (Wq^T-folded keys:  s_j = q . kq + kb)
//   vo : 48*256  @ 12288   (Wo-folded values:  ctx@Wo^T = 32 * sum a_j vo_j)
//   kb : 48      @ 24576
#define WS_KQ 0
#define WS_VO (48*DDEC)
#define WS_KB (2*48*DDEC)

#define NZBLK 2048   // zero-fill blocks; 134217728 B / 2048 = 65536 B per block

// ---------------------------------------------------------------------------
// Kernel 1: blocks 0..47 = folded-weight precompute (hides under the fill);
// blocks 48..2095 stream zeros over attn (pure-store phase, ~7 TB/s —
// 88-90% of the chip's demonstrated store ceiling).
// ---------------------------------------------------------------------------
__global__ __launch_bounds__(256) void pre_and_zero(
    const float* __restrict__ keys, const float* __restrict__ values,
    const float* __restrict__ Wk, const float* __restrict__ bk,
    const float* __restrict__ Wv, const float* __restrict__ bv,
    const float* __restrict__ Wq, const float* __restrict__ bq,
    const float* __restrict__ Wo, const int* __restrict__ pidx,
    float* __restrict__ ws, float* __restrict__ attn)
{
    const int t = threadIdx.x;

    if (blockIdx.x >= 48) {
        const int zb = blockIdx.x - 48;
        float4* p = (float4*)attn + (size_t)zb * 4096;   // 4096 float4 per block
        const float4 z4 = make_float4(0.0f, 0.0f, 0.0f, 0.0f);
        #pragma unroll
        for (int i = 0; i < 16; ++i) p[i * 256 + t] = z4;
        return;
    }

    const int blk = blockIdx.x;            // 0..47
    const int b = blk / WIN, j = blk % WIN;
    const int prev = pidx[0];
    const int col = prev + j;
    const bool valid = (col >= 0) && (col < TKL);

    __shared__ float ksh[DENC];
    __shared__ float vsh[DENC];
    __shared__ float kwsh[DATT];
    __shared__ float vwsh[DATT];

    {
        size_t base = ((size_t)b * TKL + (valid ? col : 0)) * DENC + t;
        ksh[t] = valid ? keys[base]   : 0.0f;
        vsh[t] = valid ? values[base] : 0.0f;
    }
    __syncthreads();

    if (t < DATT) {
        const float4* wrow = (const float4*)(Wk + (size_t)t * DENC);
        float acc = 0.0f;
        #pragma unroll 8
        for (int k4 = 0; k4 < DENC / 4; ++k4) {
            float4 w = wrow[k4];
            acc += w.x * ksh[k4*4+0] + w.y * ksh[k4*4+1]
                 + w.z * ksh[k4*4+2] + w.w * ksh[k4*4+3];
        }
        kwsh[t] = acc + bk[t];
    } else {
        const int c = t - DATT;
        const float4* wrow = (const float4*)(Wv + (size_t)c * DENC);
        float acc = 0.0f;
        #pragma unroll 8
        for (int k4 = 0; k4 < DENC / 4; ++k4) {
            float4 w = wrow[k4];
            acc += w.x * vsh[k4*4+0] + w.y * vsh[k4*4+1]
                 + w.z * vsh[k4*4+2] + w.w * vsh[k4*4+3];
        }
        vwsh[c] = acc + bv[c];
    }
    __syncthreads();

    float accq = 0.0f, acco = 0.0f;
    const float4* worow = (const float4*)(Wo + (size_t)t * DATT);
    #pragma unroll 4
    for (int c4 = 0; c4 < DATT / 4; ++c4) {
        float4 w = worow[c4];
        acco += w.x * vwsh[c4*4+0] + w.y * vwsh[c4*4+1]
              + w.z * vwsh[c4*4+2] + w.w * vwsh[c4*4+3];
        accq += kwsh[c4*4+0] * Wq[(size_t)(c4*4+0) * DDEC + t]
              + kwsh[c4*4+1] * Wq[(size_t)(c4*4+1) * DDEC + t]
              + kwsh[c4*4+2] * Wq[(size_t)(c4*4+2) * DDEC + t]
              + kwsh[c4*4+3] * Wq[(size_t)(c4*4+3) * DDEC + t];
    }
    ws[WS_KQ + blk * DDEC + t] = accq;
    ws[WS_VO + blk * DDEC + t] = acco;

    if (t < 64) {
        float pb = bq[t] * kwsh[t] + bq[t + 64] * kwsh[t + 64];
        #pragma unroll
        for (int off = 32; off > 0; off >>= 1) pb += __shfl_xor(pb, off, 64);
        if (t == 0) ws[WS_KB + blk] = pb;
    }
}

// ---------------------------------------------------------------------------
// Kernel 2: 1024 blocks x 32 rows, 16-lane group per 2 rows. kq/vo/bo live
// in REGISTERS (fetched once per lane from L2) — no LDS staging, no
// __syncthreads. Best-measured compute-phase variant (R8, 40.3 us total).
// ---------------------------------------------------------------------------
__device__ __forceinline__ float winval(int ww, float w0, float w1, float w2) {
    float v = (ww == 0) ? w0 : ((ww == 1) ? w1 : ((ww == 2) ? w2 : 0.0f));
    return (ww >= 0 && ww < WIN) ? v : 0.0f;
}

__global__ __launch_bounds__(256) void attn_out(
    const float* __restrict__ query, const float* __restrict__ bo,
    const int* __restrict__ pidx, const float* __restrict__ ws,
    float* __restrict__ out, float* __restrict__ attn)
{
    const int t   = threadIdx.x;
    const int G   = t >> 4;              // group 0..15
    const int sub = t & 15;
    const int blk = blockIdx.x;
    const int b   = blk >> 6;            // 64 blocks per batch (32 rows each)
    const int base = b * WIN;
    const int prev = pidx[0];

    const int rowA = blk * 32 + G;
    const int rowB = rowA + 16;

    // ---- q loads for BOTH rows first (longest latency) ----
    const float4* qA = (const float4*)query + (size_t)rowA * 64;
    const float4* qB = (const float4*)query + (size_t)rowB * 64;
    const float4 a0 = qA[ 0 + sub], a1 = qA[16 + sub],
                 a2 = qA[32 + sub], a3 = qA[48 + sub];
    const float4 b0 = qB[ 0 + sub], b1 = qB[16 + sub],
                 b2 = qB[32 + sub], b3 = qB[48 + sub];

    // ---- per-lane operand fragments into registers (L2-hot) ----
    const float4* kq4 = (const float4*)(ws + WS_KQ) + (size_t)base * 64;
    const float4* vo4 = (const float4*)(ws + WS_VO) + (size_t)base * 64;
    const float4* bo4 = (const float4*)bo;

    float4 K0[4], K1[4], K2[4], V0[4], V1[4], V2[4], B4[4];
    #pragma unroll
    for (int k = 0; k < 4; ++k) {
        K0[k] = kq4[  0 + k * 16 + sub];
        K1[k] = kq4[ 64 + k * 16 + sub];
        K2[k] = kq4[128 + k * 16 + sub];
        V0[k] = vo4[  0 + k * 16 + sub];
        V1[k] = vo4[ 64 + k * 16 + sub];
        V2[k] = vo4[128 + k * 16 + sub];
        B4[k] = bo4[k * 16 + sub];
    }
    const float kb0 = ws[WS_KB + base + 0];
    const float kb1 = ws[WS_KB + base + 1];
    const float kb2 = ws[WS_KB + base + 2];

    // ---- window float4 indices (uniform) ----
    int lo = prev < 0 ? 0 : prev;
    int hi = prev + (WIN - 1) > TKL - 1 ? TKL - 1 : prev + (WIN - 1);
    int f0 = -1, f1 = -1;
    if (lo <= hi) { f0 = lo >> 2; f1 = hi >> 2; }

    const bool v0 = (prev + 0 >= 0) && (prev + 0 < TKL);
    const bool v1 = (prev + 1 >= 0) && (prev + 1 < TKL);
    const bool v2 = (prev + 2 >= 0) && (prev + 2 < TKL);

    const float CTX_SCALE = 32.0f;            // Tk * sqrt(1/Tk) = sqrt(1024)
    const float RSQ2 = 0.70710678118654752f;  // sqrt(0.5)
    const float NEG = -3.0e38f;

    auto do_row = [&](int row, const float4 q0, const float4 q1,
                      const float4 q2, const float4 q3) {
        float p0, p1, p2;
        p0  = q0.x*K0[0].x + q0.y*K0[0].y + q0.z*K0[0].z + q0.w*K0[0].w;
        p1  = q0.x*K1[0].x + q0.y*K1[0].y + q0.z*K1[0].z + q0.w*K1[0].w;
        p2  = q0.x*K2[0].x + q0.y*K2[0].y + q0.z*K2[0].z + q0.w*K2[0].w;
        p0 += q1.x*K0[1].x + q1.y*K0[1].y + q1.z*K0[1].z + q1.w*K0[1].w;
        p1 += q1.x*K1[1].x + q1.y*K1[1].y + q1.z*K1[1].z + q1.w*K1[1].w;
        p2 += q1.x*K2[1].x + q1.y*K2[1].y + q1.z*K2[1].z + q1.w*K2[1].w;
        p0 += q2.x*K0[2].x + q2.y*K0[2].y + q2.z*K0[2].z + q2.w*K0[2].w;
        p1 += q2.x*K1[2].x + q2.y*K1[2].y + q2.z*K1[2].z + q2.w*K1[2].w;
        p2 += q2.x*K2[2].x + q2.y*K2[2].y + q2.z*K2[2].z + q2.w*K2[2].w;
        p0 += q3.x*K0[3].x + q3.y*K0[3].y + q3.z*K0[3].z + q3.w*K0[3].w;
        p1 += q3.x*K1[3].x + q3.y*K1[3].y + q3.z*K1[3].z + q3.w*K1[3].w;
        p2 += q3.x*K2[3].x + q3.y*K2[3].y + q3.z*K2[3].z + q3.w*K2[3].w;

        #pragma unroll
        for (int off = 8; off > 0; off >>= 1) {
            p0 += __shfl_xor(p0, off, 64);
            p1 += __shfl_xor(p1, off, 64);
            p2 += __shfl_xor(p2, off, 64);
        }

        float s0 = v0 ? (p0 + kb0) : NEG;
        float s1 = v1 ? (p1 + kb1) : NEG;
        float s2 = v2 ? (p2 + kb2) : NEG;

        const float m  = fmaxf(s0, fmaxf(s1, s2));
        const float e0 = v0 ? __expf(s0 - m) : 0.0f;
        const float e1 = v1 ? __expf(s1 - m) : 0.0f;
        const float e2 = v2 ? __expf(s2 - m) : 0.0f;
        const float inv = 1.0f / (e0 + e1 + e2);
        const float w0 = e0 * inv, w1 = e1 * inv, w2 = e2 * inv;

        float4* orow = (float4*)(out + (size_t)row * DDEC);
        #pragma unroll
        for (int k = 0; k < 4; ++k) {
            const float4 qq = (k == 0) ? q0 : (k == 1) ? q1 : (k == 2) ? q2 : q3;
            float4 o;
            o.x = (CTX_SCALE * (w0*V0[k].x + w1*V1[k].x + w2*V2[k].x) + B4[k].x + qq.x) * RSQ2;
            o.y = (CTX_SCALE * (w0*V0[k].y + w1*V1[k].y + w2*V2[k].y) + B4[k].y + qq.y) * RSQ2;
            o.z = (CTX_SCALE * (w0*V0[k].z + w1*V1[k].z + w2*V2[k].z) + B4[k].z + qq.z) * RSQ2;
            o.w = (CTX_SCALE * (w0*V0[k].w + w1*V1[k].w + w2*V2[k].w) + B4[k].w + qq.w) * RSQ2;
            orow[k * 16 + sub] = o;
        }

        if (f0 >= 0) {
            float4* arow = (float4*)(attn + (size_t)row * TKL);
            if ((f0 & 15) == sub) {
                const int c0 = f0 * 4;
                float4 pz;
                pz.x = winval(c0 + 0 - prev, w0, w1, w2);
                pz.y = winval(c0 + 1 - prev, w0, w1, w2);
                pz.z = winval(c0 + 2 - prev, w0, w1, w2);
                pz.w = winval(c0 + 3 - prev, w0, w1, w2);
                arow[f0] = pz;
            }
            if (f1 != f0 && (f1 & 15) == sub) {
                const int c0 = f1 * 4;
                float4 pz;
                pz.x = winval(c0 + 0 - prev, w0, w1, w2);
                pz.y = winval(c0 + 1 - prev, w0, w1, w2);
                pz.z = winval(c0 + 2 - prev, w0, w1, w2);
                pz.w = winval(c0 + 3 - prev, w0, w1, w2);
                arow[f1] = pz;
            }
        }
    };

    do_row(rowA, a0, a1, a2, a3);
    do_row(rowB, b0, b1, b2, b3);
}

extern "C" void kernel_launch(void* const* d_in, const int* in_sizes, int n_in,
                              void* d_out, int out_size, void* d_ws, size_t ws_size,
                              hipStream_t stream)
{
    const float* query  = (const float*)d_in[0];
    const float* keys   = (const float*)d_in[1];
    const float* values = (const float*)d_in[2];
    const float* Wq     = (const float*)d_in[3];
    const float* bq     = (const float*)d_in[4];
    const float* Wk     = (const float*)d_in[5];
    const float* bk     = (const float*)d_in[6];
    const float* Wv     = (const float*)d_in[7];
    const float* bv     = (const float*)d_in[8];
    const float* Wo     = (const float*)d_in[9];
    const float* bo     = (const float*)d_in[10];
    const int*   pidx   = (const int*)d_in[11];

    float* ws   = (float*)d_ws;
    float* out  = (float*)d_out;
    float* attn = out + (size_t)BATCH * TQL * DDEC;

    pre_and_zero<<<48 + NZBLK, 256, 0, stream>>>(keys, values, Wk, bk, Wv, bv,
                                                 Wq, bq, Wo, pidx, ws, attn);
    attn_out<<<BATCH * TQL / 32, 256, 0, stream>>>(query, bo, pidx, ws, out, attn);
}